// Round 14
// baseline (186.047 us; speedup 1.0000x reference)
//
#include <hip/hip_runtime.h>

static constexpr int   Bn      = 32;
static constexpr int   Tn      = 2000;
static constexpr int   Hn      = 512;
static constexpr int   Ln      = 256;     // max_label_len
static constexpr float kThresh = 0.95f;
static constexpr int   TCHUNK  = 40;
static constexpr int   NTCH    = Tn / TCHUNK;   // 50

// ---------------------------------------------------------------------------
// K0: transpose alphas [B][T] -> at4 [T/4][B] float4, where at4[q][b] packs
// row b's 4 consecutive alphas a[4q..4q+3]. 256 KB total. This makes the
// lockstep scan's per-chunk prefetch PERFECTLY coalesced: lane b reads
// at4[q][b] -> lanes 0-31 hit consecutive 16 B (one 512 B transaction).
// R13's killer was exactly this load pattern (per-lane own-row reads = 32
// scattered lines per instruction -> 176 us, VALUBusy 0.03%).
// ---------------------------------------------------------------------------
__global__ __launch_bounds__(256) void cif_transpose_kernel(
    const float* __restrict__ alphas,
    float4* __restrict__ at4) {          // [Tn/4][Bn]
  const int b = blockIdx.x;
  const float4* __restrict__ arow =
      reinterpret_cast<const float4*>(alphas + (size_t)b * Tn);
  for (int q = threadIdx.x; q < Tn / 4; q += 256)
    at4[q * Bn + b] = arow[q];           // read coalesced; write L2-absorbed
}

// ---------------------------------------------------------------------------
// K1: ONE block; lane b (lanes 32-63 mirror) runs row b's serial
// integrate-and-fire chain -- all 32 row-chains advance in lockstep, so the
// whole scan is ONE 2000-step dependent add->cmp->cndmask chain. Per chunk:
// 10 coalesced float4 loads from at4 (double-buffered one chunk ahead).
// Fire events go to an LDS table via exec-masked ds_write (lgkm-ordered; no
// vmcnt drain inside the chain), bulk-flushed coalesced at the end.
// Bit-exact: per-row f32 op order identical to reference (absmax 0.0 in
// R8-R13).
// ---------------------------------------------------------------------------
__global__ __launch_bounds__(64, 1) void cif_scan32_kernel(
    const float4* __restrict__ at4,      // [Tn/4][Bn]
    int*   __restrict__ tf,     // [Bn][Ln] fire timestep
    float* __restrict__ cwv,    // [Bn][Ln] closing weight (dist_completion)
    float* __restrict__ remv,   // [Bn][Ln] remainder weight (opens next seg)
    int*   __restrict__ fcnt) { // [Bn]
  const int lane = threadIdx.x;
  const int b    = lane & (Bn - 1);          // lanes 32-63 mirror rows
  const bool owner = (lane < Bn);

  __shared__ __align__(16) int   tf_lds[Bn][Ln];
  __shared__ __align__(16) float cw_lds[Bn][Ln];
  __shared__ __align__(16) float rm_lds[Bn][Ln];

  // Zero-init LDS (vectorized) so the copy-out is deterministic everywhere.
  {
    int4*   tz = reinterpret_cast<int4*>(&tf_lds[0][0]);
    float4* cz = reinterpret_cast<float4*>(&cw_lds[0][0]);
    float4* rz = reinterpret_cast<float4*>(&rm_lds[0][0]);
    const float4 z4 = make_float4(0.f, 0.f, 0.f, 0.f);
    for (int i = lane; i < Bn * Ln / 4; i += 64) {
      tz[i] = make_int4(0, 0, 0, 0);
      cz[i] = z4;
      rz[i] = z4;
    }
  }
  __syncthreads();

  constexpr int CV = TCHUNK / 4;             // 10 float4 per chunk per lane

  float I  = 0.0f;                           // integrate
  int   fc = 0;

  float4 cur[CV], nxt[CV];
#pragma unroll
  for (int i = 0; i < CV; ++i) cur[i] = at4[i * Bn + b];   // coalesced

  for (int c = 0; c < NTCH; ++c) {
    if (c + 1 < NTCH) {
#pragma unroll
      for (int i = 0; i < CV; ++i)
        nxt[i] = at4[((c + 1) * CV + i) * Bn + b];         // coalesced
    }
    const int tbase = c * TCHUNK;
#pragma unroll
    for (int i = 0; i < CV; ++i) {
      const float a4[4] = {cur[i].x, cur[i].y, cur[i].z, cur[i].w};
#pragma unroll
      for (int j = 0; j < 4; ++j) {
        const float a     = a4[j];
        const float integ = I + a;           // reference op order
        const bool  fire  = integ > kThresh; // per-lane divergent
        if (fire && owner && fc < Ln) {      // LDS only: no vmcnt in chain
          const float cw  = 1.0f - I;        // dist_completion
          tf_lds[b][fc] = tbase + i * 4 + j;
          cw_lds[b][fc] = cw;
          rm_lds[b][fc] = a - cw;            // remainds
        }
        I  = fire ? (integ - 1.0f) : integ;  // proven select form
        fc += fire ? 1 : 0;
      }
    }
#pragma unroll
    for (int i = 0; i < CV; ++i) cur[i] = nxt[i];
  }
  if (owner) fcnt[b] = fc;
  __syncthreads();

  // Coalesced bulk flush LDS -> global (3 x 32 KB).
  {
    const int4*   ts = reinterpret_cast<const int4*>(&tf_lds[0][0]);
    const float4* cs = reinterpret_cast<const float4*>(&cw_lds[0][0]);
    const float4* rs = reinterpret_cast<const float4*>(&rm_lds[0][0]);
    int4*   tg = reinterpret_cast<int4*>(tf);
    float4* cg = reinterpret_cast<float4*>(cwv);
    float4* rg = reinterpret_cast<float4*>(remv);
    for (int i = lane; i < Bn * Ln / 4; i += 64) {
      tg[i] = ts[i];
      cg[i] = cs[i];
      rg[i] = rs[i];
    }
  }
}

// ---------------------------------------------------------------------------
// K2 (unchanged, proven bit-exact): block (s, b) EXCLUSIVELY owns out[b][s].
// Segment s spans (t_prev, t_hi]: rem[s-1]*h[t_prev] + raw-alpha interior +
// cw[s]*h[t_hi], ascending t. Plain float4 stores, no atomics; s >=
// min(fcnt,Ln) slots store zeros -> no pre-zero pass needed.
// ---------------------------------------------------------------------------
__global__ __launch_bounds__(128) void cif_seg_accum_kernel(
    const float* __restrict__ hidden,
    const float* __restrict__ alphas,
    const int*   __restrict__ tf,
    const float* __restrict__ cwv,
    const float* __restrict__ remv,
    const int*   __restrict__ fcnt,
    float* __restrict__ out) {
  const int s   = blockIdx.x;          // 0..Ln-1
  const int b   = blockIdx.y;          // 0..Bn-1
  const int col = threadIdx.x * 4;

  const int fb    = fcnt[b];
  const int limit = fb < Ln ? fb : Ln;

  float* __restrict__ o = out + ((size_t)b * Ln + s) * Hn + col;

  if (s >= limit) {                    // never-fired slot: emit zeros
    *reinterpret_cast<float4*>(o) = make_float4(0.f, 0.f, 0.f, 0.f);
    return;
  }

  const int t_hi   = tf[b * Ln + s];
  const int t_prev = (s > 0) ? tf[b * Ln + s - 1] : -1;

  const float* __restrict__ hbase = hidden + (size_t)b * Tn * Hn + col;
  const float* __restrict__ arow  = alphas + (size_t)b * Tn;

  float4 acc = make_float4(0.f, 0.f, 0.f, 0.f);

  if (s > 0) {                         // opening: frame = rem * h[t_prev]
    const float r  = remv[b * Ln + s - 1];
    const float4 h = *reinterpret_cast<const float4*>(hbase + (size_t)t_prev * Hn);
    acc.x = r * h.x; acc.y = r * h.y; acc.z = r * h.z; acc.w = r * h.w;
  }
  for (int t = t_prev + 1; t < t_hi; ++t) {   // interior: weight = raw alpha
    const float a  = arow[t];
    const float4 h = *reinterpret_cast<const float4*>(hbase + (size_t)t * Hn);
    acc.x += a * h.x; acc.y += a * h.y; acc.z += a * h.z; acc.w += a * h.w;
  }
  {                                    // closing: weight = dist_completion
    const float c  = cwv[b * Ln + s];
    const float4 h = *reinterpret_cast<const float4*>(hbase + (size_t)t_hi * Hn);
    acc.x += c * h.x; acc.y += c * h.y; acc.z += c * h.z; acc.w += c * h.w;
  }
  *reinterpret_cast<float4*>(o) = acc;
}

extern "C" void kernel_launch(void* const* d_in, const int* in_sizes, int n_in,
                              void* d_out, int out_size, void* d_ws, size_t ws_size,
                              hipStream_t stream) {
  const float* hidden = (const float*)d_in[0];
  const float* alphas = (const float*)d_in[1];
  float* out = (float*)d_out;

  // ws layout: at4[Tn/4][Bn] float4 (256 KB) | tf[B][Ln] i32 (32 KB)
  //          | cw[B][Ln] f32 (32 KB) | rem[B][Ln] f32 (32 KB) | fcnt[B] i32
  float4* at4  = (float4*)d_ws;
  int*    tf   = (int*)(at4 + (size_t)(Tn / 4) * Bn);
  float*  cwv  = (float*)(tf + (size_t)Bn * Ln);
  float*  remv = cwv + (size_t)Bn * Ln;
  int*    fcnt = (int*)(remv + (size_t)Bn * Ln);

  cif_transpose_kernel<<<Bn, 256, 0, stream>>>(alphas, at4);
  cif_scan32_kernel<<<1, 64, 0, stream>>>(at4, tf, cwv, remv, fcnt);

  dim3 grid(Ln, Bn);   // 8192 independent blocks, one per output slot
  cif_seg_accum_kernel<<<grid, 128, 0, stream>>>(hidden, alphas, tf, cwv,
                                                 remv, fcnt, out);
}

// Round 15
// 80.569 us; speedup vs baseline: 2.3092x; 2.3092x over previous
//
#include <hip/hip_runtime.h>

static constexpr int   Bn      = 32;
static constexpr int   Tn      = 2000;
static constexpr int   Hn      = 512;
static constexpr int   Ln      = 256;     // max_label_len
static constexpr float kThresh = 0.95f;
static constexpr int   TCHUNK  = 40;
static constexpr int   NTCH    = Tn / TCHUNK;   // 50
static constexpr int   NSTREAM = 2016;          // streamer blocks after 32 scans

// ---------------------------------------------------------------------------
// K1: scan (blocks 0..31, one wave per row — R10's proven bit-exact kernel)
// + DVFS/streamer padding (blocks 32..2047): one grid-stride read pass over
// hidden, no writes, no sync, loads kept live with asm (rule #17).
// R11-R14 synthesis: every scan structure shows ~4x more "cycles"/step than
// its issue/latency model (46 vs ~12; lockstep 200+ vs ~30), while harness
// fills on the same chip hit 7 TB/s -> the scan phase runs at IDLE CLOCKS
// (~650 MHz; 32 near-idle waves don't trigger a DVFS boost). The streamers
// give the power manager a reason to clock up, and pre-warm hidden for K2.
// If the theory is wrong they hide under the 38.7 us scan: free experiment.
// ---------------------------------------------------------------------------
__global__ __launch_bounds__(256, 1) void cif_scan_stream_kernel(
    const float* __restrict__ alphas,
    const float* __restrict__ hidden,
    int*   __restrict__ tf,     // [Bn][Ln] fire timestep
    float* __restrict__ cwv,    // [Bn][Ln] closing weight (dist_completion)
    float* __restrict__ remv,   // [Bn][Ln] remainder weight (opens next seg)
    int*   __restrict__ fcnt) { // [Bn]
  if (blockIdx.x >= Bn) {
    // ---- streamer: one read pass over hidden (131 MB across 2016 blocks) --
    const size_t n4   = (size_t)Bn * Tn * Hn / 4;
    const size_t base = (size_t)(blockIdx.x - Bn) * 256 + threadIdx.x;
    const size_t step = (size_t)NSTREAM * 256;
    const float4* __restrict__ hp = reinterpret_cast<const float4*>(hidden);
    float4 acc = make_float4(0.f, 0.f, 0.f, 0.f);
    for (size_t i = base; i < n4; i += step) {
      const float4 v = hp[i];
      acc.x += v.x; acc.y += v.y; acc.z += v.z; acc.w += v.w;
    }
    asm volatile("" :: "v"(acc.x), "v"(acc.y), "v"(acc.z), "v"(acc.w));
    return;
  }
  if (threadIdx.x >= 64) return;       // scan uses one wave per block

  // ---- scan: R10's kernel verbatim (proven absmax 0.0) ----
  const int b    = blockIdx.x;
  const int lane = threadIdx.x;
  const float4* __restrict__ arow =
      reinterpret_cast<const float4*>(alphas + (size_t)b * Tn);
  constexpr int CV = TCHUNK / 4;   // 10 float4 per chunk

  // Phase A: serial scan, register-only; lane c snapshots chunk c's state.
  float integrate = 0.0f;
  int   fc        = 0;
  float my_int    = 0.0f;
  int   my_fc     = 0;

  float4 cur[CV], nxt[CV];
#pragma unroll
  for (int i = 0; i < CV; ++i) cur[i] = arow[i];

  for (int c = 0; c < NTCH; ++c) {
    if (c + 1 < NTCH) {
#pragma unroll
      for (int i = 0; i < CV; ++i) nxt[i] = arow[(c + 1) * CV + i];
    }
    const bool mine = (c == lane);
    my_int = mine ? integrate : my_int;
    my_fc  = mine ? fc        : my_fc;
#pragma unroll
    for (int i = 0; i < CV; ++i) {
      const float a4[4] = {cur[i].x, cur[i].y, cur[i].z, cur[i].w};
#pragma unroll
      for (int j = 0; j < 4; ++j) {
        const float integ = integrate + a4[j];    // reference op order
        const bool  fire  = integ > kThresh;
        integrate = fire ? (integ - 1.0f) : integ;
        fc += fire ? 1 : 0;
      }
    }
#pragma unroll
    for (int i = 0; i < CV; ++i) cur[i] = nxt[i];
  }
  if (lane == 0) fcnt[b] = fc;

  // Phase B: lane c replays chunk c from its bit-exact snapshot -> fire table.
  if (lane < NTCH) {
    const int t0 = lane * TCHUNK;
    const float4* __restrict__ crow =
        reinterpret_cast<const float4*>(alphas + (size_t)b * Tn + t0);
    float av[TCHUNK];
#pragma unroll
    for (int i = 0; i < CV; ++i) {
      const float4 v = crow[i];
      av[4 * i + 0] = v.x; av[4 * i + 1] = v.y;
      av[4 * i + 2] = v.z; av[4 * i + 3] = v.w;
    }
    float ig = my_int;
    int   s  = my_fc;
#pragma unroll
    for (int k = 0; k < TCHUNK; ++k) {
      const float a     = av[k];
      const float integ = ig + a;                 // reference op order
      const bool  fire  = integ > kThresh;
      if (fire) {
        if (s < Ln) {
          const float cw  = 1.0f - ig;            // dist_completion
          const float rem = a - cw;               // remainds
          tf  [b * Ln + s] = t0 + k;
          cwv [b * Ln + s] = cw;
          remv[b * Ln + s] = rem;
        }
        s += 1;
        ig = integ - 1.0f;
      } else {
        ig = integ;
      }
    }
  }
}

// ---------------------------------------------------------------------------
// K2 (unchanged, proven bit-exact): block (s, b) EXCLUSIVELY owns out[b][s].
// Segment s spans (t_prev, t_hi]: rem[s-1]*h[t_prev] + raw-alpha interior +
// cw[s]*h[t_hi], ascending t. Plain float4 stores, no atomics; s >=
// min(fcnt,Ln) slots store zeros -> no pre-zero pass needed.
// ---------------------------------------------------------------------------
__global__ __launch_bounds__(128) void cif_seg_accum_kernel(
    const float* __restrict__ hidden,
    const float* __restrict__ alphas,
    const int*   __restrict__ tf,
    const float* __restrict__ cwv,
    const float* __restrict__ remv,
    const int*   __restrict__ fcnt,
    float* __restrict__ out) {
  const int s   = blockIdx.x;          // 0..Ln-1
  const int b   = blockIdx.y;          // 0..Bn-1
  const int col = threadIdx.x * 4;

  const int fb    = fcnt[b];
  const int limit = fb < Ln ? fb : Ln;

  float* __restrict__ o = out + ((size_t)b * Ln + s) * Hn + col;

  if (s >= limit) {                    // never-fired slot: emit zeros
    *reinterpret_cast<float4*>(o) = make_float4(0.f, 0.f, 0.f, 0.f);
    return;
  }

  const int t_hi   = tf[b * Ln + s];
  const int t_prev = (s > 0) ? tf[b * Ln + s - 1] : -1;

  const float* __restrict__ hbase = hidden + (size_t)b * Tn * Hn + col;
  const float* __restrict__ arow  = alphas + (size_t)b * Tn;

  float4 acc = make_float4(0.f, 0.f, 0.f, 0.f);

  if (s > 0) {                         // opening: frame = rem * h[t_prev]
    const float r  = remv[b * Ln + s - 1];
    const float4 h = *reinterpret_cast<const float4*>(hbase + (size_t)t_prev * Hn);
    acc.x = r * h.x; acc.y = r * h.y; acc.z = r * h.z; acc.w = r * h.w;
  }
  for (int t = t_prev + 1; t < t_hi; ++t) {   // interior: weight = raw alpha
    const float a  = arow[t];
    const float4 h = *reinterpret_cast<const float4*>(hbase + (size_t)t * Hn);
    acc.x += a * h.x; acc.y += a * h.y; acc.z += a * h.z; acc.w += a * h.w;
  }
  {                                    // closing: weight = dist_completion
    const float c  = cwv[b * Ln + s];
    const float4 h = *reinterpret_cast<const float4*>(hbase + (size_t)t_hi * Hn);
    acc.x += c * h.x; acc.y += c * h.y; acc.z += c * h.z; acc.w += c * h.w;
  }
  *reinterpret_cast<float4*>(o) = acc;
}

extern "C" void kernel_launch(void* const* d_in, const int* in_sizes, int n_in,
                              void* d_out, int out_size, void* d_ws, size_t ws_size,
                              hipStream_t stream) {
  const float* hidden = (const float*)d_in[0];
  const float* alphas = (const float*)d_in[1];
  float* out = (float*)d_out;

  // ws layout: tf[B][Ln] i32 (32 KB) | cw[B][Ln] f32 | rem[B][Ln] f32 | fcnt[B]
  int*   tf   = (int*)d_ws;
  float* cwv  = (float*)(tf + (size_t)Bn * Ln);
  float* remv = cwv + (size_t)Bn * Ln;
  int*   fcnt = (int*)(remv + (size_t)Bn * Ln);

  cif_scan_stream_kernel<<<Bn + NSTREAM, 256, 0, stream>>>(alphas, hidden,
                                                           tf, cwv, remv, fcnt);

  dim3 grid(Ln, Bn);   // 8192 independent blocks, one per output slot
  cif_seg_accum_kernel<<<grid, 128, 0, stream>>>(hidden, alphas, tf, cwv,
                                                 remv, fcnt, out);
}

// Round 16
// 77.138 us; speedup vs baseline: 2.4119x; 1.0445x over previous
//
#include <hip/hip_runtime.h>

static constexpr int   Bn      = 32;
static constexpr int   Tn      = 2000;
static constexpr int   Hn      = 512;
static constexpr int   Ln      = 256;     // max_label_len
static constexpr float kThresh = 0.95f;
static constexpr int   TCHUNK  = 40;
static constexpr int   NTCH    = Tn / TCHUNK;   // 50
static constexpr int   NSTREAM = 2048;          // 64-thr streamer blocks
static constexpr size_t STREAM_N4 = (size_t)48 * 1024 * 1024 / 16;  // 48 MB

// ---------------------------------------------------------------------------
// K1: scan (blocks 0..31 = R10's proven kernel, byte-identical) + DVFS
// streamer blocks (32..2079) reading 48 MB of hidden.
// R15 lesson: ANY kernel of this family built with >=128-thread blocks gets
// its VGPR allocation collapsed (R9:12, R12:8, R15:28) and the scan's 80-reg
// alpha double-buffer spills into the serial chain. Only 64-thread +
// __launch_bounds__(64,1) has ever produced the honest VGPR=132 -> streamers
// here are 64-thread blocks of the SAME kernel.
// Streamer sizing: 48 MB even at idle-clock ~1.5 TB/s is ~32 us < the
// 38.7 us scan -> streamers can never become the critical path; at boosted
// clocks they finish in ~8 us. Purpose: give the power manager sustained
// chip-wide load so the near-idle serial scan phase doesn't sit at ~600 MHz
// (R11-R14 synthesis: every scan variant runs ~4x its cycle model while
// harness fills on the same chip sustain 7 TB/s), plus pre-warm hidden.
// ---------------------------------------------------------------------------
__global__ __launch_bounds__(64, 1) void cif_scan_stream_kernel(
    const float* __restrict__ alphas,
    const float* __restrict__ hidden,
    int*   __restrict__ tf,     // [Bn][Ln] fire timestep
    float* __restrict__ cwv,    // [Bn][Ln] closing weight (dist_completion)
    float* __restrict__ remv,   // [Bn][Ln] remainder weight (opens next seg)
    int*   __restrict__ fcnt) { // [Bn]
  if (blockIdx.x >= Bn) {
    // ---- streamer: read 48 MB of hidden, keep loads live (rule #17) ----
    const float4* __restrict__ hp = reinterpret_cast<const float4*>(hidden);
    size_t       i    = (size_t)(blockIdx.x - Bn) * 64 + threadIdx.x;
    const size_t step = (size_t)NSTREAM * 64;
    float4 acc = make_float4(0.f, 0.f, 0.f, 0.f);
    for (; i < STREAM_N4; i += step) {
      const float4 v = hp[i];
      acc.x += v.x; acc.y += v.y; acc.z += v.z; acc.w += v.w;
    }
    asm volatile("" :: "v"(acc.x), "v"(acc.y), "v"(acc.z), "v"(acc.w));
    return;
  }

  // ---- scan: R10's kernel verbatim (proven absmax 0.0, VGPR 132) ----
  const int b    = blockIdx.x;
  const int lane = threadIdx.x;
  const float4* __restrict__ arow =
      reinterpret_cast<const float4*>(alphas + (size_t)b * Tn);
  constexpr int CV = TCHUNK / 4;   // 10 float4 per chunk

  // Phase A: serial scan, register-only; lane c snapshots chunk c's state.
  float integrate = 0.0f;
  int   fc        = 0;
  float my_int    = 0.0f;
  int   my_fc     = 0;

  float4 cur[CV], nxt[CV];
#pragma unroll
  for (int i = 0; i < CV; ++i) cur[i] = arow[i];

  for (int c = 0; c < NTCH; ++c) {
    if (c + 1 < NTCH) {
#pragma unroll
      for (int i = 0; i < CV; ++i) nxt[i] = arow[(c + 1) * CV + i];
    }
    const bool mine = (c == lane);
    my_int = mine ? integrate : my_int;
    my_fc  = mine ? fc        : my_fc;
#pragma unroll
    for (int i = 0; i < CV; ++i) {
      const float a4[4] = {cur[i].x, cur[i].y, cur[i].z, cur[i].w};
#pragma unroll
      for (int j = 0; j < 4; ++j) {
        const float integ = integrate + a4[j];    // reference op order
        const bool  fire  = integ > kThresh;
        integrate = fire ? (integ - 1.0f) : integ;
        fc += fire ? 1 : 0;
      }
    }
#pragma unroll
    for (int i = 0; i < CV; ++i) cur[i] = nxt[i];
  }
  if (lane == 0) fcnt[b] = fc;

  // Phase B: lane c replays chunk c from its bit-exact snapshot -> fire table.
  if (lane < NTCH) {
    const int t0 = lane * TCHUNK;
    const float4* __restrict__ crow =
        reinterpret_cast<const float4*>(alphas + (size_t)b * Tn + t0);
    float av[TCHUNK];
#pragma unroll
    for (int i = 0; i < CV; ++i) {
      const float4 v = crow[i];
      av[4 * i + 0] = v.x; av[4 * i + 1] = v.y;
      av[4 * i + 2] = v.z; av[4 * i + 3] = v.w;
    }
    float ig = my_int;
    int   s  = my_fc;
#pragma unroll
    for (int k = 0; k < TCHUNK; ++k) {
      const float a     = av[k];
      const float integ = ig + a;                 // reference op order
      const bool  fire  = integ > kThresh;
      if (fire) {
        if (s < Ln) {
          const float cw  = 1.0f - ig;            // dist_completion
          const float rem = a - cw;               // remainds
          tf  [b * Ln + s] = t0 + k;
          cwv [b * Ln + s] = cw;
          remv[b * Ln + s] = rem;
        }
        s += 1;
        ig = integ - 1.0f;
      } else {
        ig = integ;
      }
    }
  }
}

// ---------------------------------------------------------------------------
// K2 (unchanged, proven bit-exact): block (s, b) EXCLUSIVELY owns out[b][s].
// Segment s spans (t_prev, t_hi]: rem[s-1]*h[t_prev] + raw-alpha interior +
// cw[s]*h[t_hi], ascending t. Plain float4 stores, no atomics; s >=
// min(fcnt,Ln) slots store zeros -> no pre-zero pass needed.
// ---------------------------------------------------------------------------
__global__ __launch_bounds__(128) void cif_seg_accum_kernel(
    const float* __restrict__ hidden,
    const float* __restrict__ alphas,
    const int*   __restrict__ tf,
    const float* __restrict__ cwv,
    const float* __restrict__ remv,
    const int*   __restrict__ fcnt,
    float* __restrict__ out) {
  const int s   = blockIdx.x;          // 0..Ln-1
  const int b   = blockIdx.y;          // 0..Bn-1
  const int col = threadIdx.x * 4;

  const int fb    = fcnt[b];
  const int limit = fb < Ln ? fb : Ln;

  float* __restrict__ o = out + ((size_t)b * Ln + s) * Hn + col;

  if (s >= limit) {                    // never-fired slot: emit zeros
    *reinterpret_cast<float4*>(o) = make_float4(0.f, 0.f, 0.f, 0.f);
    return;
  }

  const int t_hi   = tf[b * Ln + s];
  const int t_prev = (s > 0) ? tf[b * Ln + s - 1] : -1;

  const float* __restrict__ hbase = hidden + (size_t)b * Tn * Hn + col;
  const float* __restrict__ arow  = alphas + (size_t)b * Tn;

  float4 acc = make_float4(0.f, 0.f, 0.f, 0.f);

  if (s > 0) {                         // opening: frame = rem * h[t_prev]
    const float r  = remv[b * Ln + s - 1];
    const float4 h = *reinterpret_cast<const float4*>(hbase + (size_t)t_prev * Hn);
    acc.x = r * h.x; acc.y = r * h.y; acc.z = r * h.z; acc.w = r * h.w;
  }
  for (int t = t_prev + 1; t < t_hi; ++t) {   // interior: weight = raw alpha
    const float a  = arow[t];
    const float4 h = *reinterpret_cast<const float4*>(hbase + (size_t)t * Hn);
    acc.x += a * h.x; acc.y += a * h.y; acc.z += a * h.z; acc.w += a * h.w;
  }
  {                                    // closing: weight = dist_completion
    const float c  = cwv[b * Ln + s];
    const float4 h = *reinterpret_cast<const float4*>(hbase + (size_t)t_hi * Hn);
    acc.x += c * h.x; acc.y += c * h.y; acc.z += c * h.z; acc.w += c * h.w;
  }
  *reinterpret_cast<float4*>(o) = acc;
}

extern "C" void kernel_launch(void* const* d_in, const int* in_sizes, int n_in,
                              void* d_out, int out_size, void* d_ws, size_t ws_size,
                              hipStream_t stream) {
  const float* hidden = (const float*)d_in[0];
  const float* alphas = (const float*)d_in[1];
  float* out = (float*)d_out;

  // ws layout: tf[B][Ln] i32 (32 KB) | cw[B][Ln] f32 | rem[B][Ln] f32 | fcnt[B]
  int*   tf   = (int*)d_ws;
  float* cwv  = (float*)(tf + (size_t)Bn * Ln);
  float* remv = cwv + (size_t)Bn * Ln;
  int*   fcnt = (int*)(remv + (size_t)Bn * Ln);

  cif_scan_stream_kernel<<<Bn + NSTREAM, 64, 0, stream>>>(alphas, hidden,
                                                          tf, cwv, remv, fcnt);

  dim3 grid(Ln, Bn);   // 8192 independent blocks, one per output slot
  cif_seg_accum_kernel<<<grid, 128, 0, stream>>>(hidden, alphas, tf, cwv,
                                                 remv, fcnt, out);
}

// Round 18
// 70.012 us; speedup vs baseline: 2.6574x; 1.1018x over previous
//
#include <hip/hip_runtime.h>
#include <stdint.h>

static constexpr int   Bn      = 32;
static constexpr int   Tn      = 2000;
static constexpr int   Hn      = 512;
static constexpr int   Ln      = 256;     // max_label_len
static constexpr float kThresh = 0.95f;
static constexpr int   TCHUNK  = 40;
static constexpr int   NTCH    = Tn / TCHUNK;   // 50
static constexpr int   MSTRIDE = 64;            // meta entries per row (padded)
static constexpr unsigned PUBF = 0x40000000u;   // published flag (low word)

// ---------------------------------------------------------------------------
// Fused producer-consumer CIF, exclusive-ownership design (R17 fixed:
// macro-parameter 'w' collided with .w member access; now lambdas).
//
// Producers (blocks 0..31, one wave per row): register-only serial chain.
// Per 40-step chunk, lane 0 publishes ONE relaxed 8-byte atomic store:
// packed (integrate_bits, PUB|fc) = exact chunk-start state. The meta IS
// the readiness flag -> no release fence, no vmcnt drain in the chain.
//
// Consumers (blocks 32..1631, one per (chunk tc, row b)): wait for meta[tc],
// bit-exactly replay chunk tc from the packed state, and EXCLUSIVELY own
// every output segment that CLOSES in chunk tc (walk-back re-derives the
// straddling segment's opening; ascending-t accumulation = R8-K2's exact
// absmax-0.0 form). Open tails are owned by the next chunk's consumer;
// tc=49 consumers zero-fill slots [fc_final, 256). No atomics, no pre-zero,
// every output element written exactly once per call.
//
// Safety: ALL blocks 64-thread (>=128-thread branchy kernels collapsed VGPR
// to 8-28 in R9/R12/R15 and spilled the producer); __launch_bounds__(64,2)
// -> all 1632 blocks co-resident -> no spin deadlock. Meta (16 KB) memset 0
// per call (poison 0xAA reads as published otherwise).
// ---------------------------------------------------------------------------
__global__ __launch_bounds__(64, 2) void cif_fused_kernel(
    const float* __restrict__ hidden,
    const float* __restrict__ alphas,
    uint64_t* __restrict__ meta,     // [Bn*MSTRIDE]
    float* __restrict__ out) {
  const int lane = threadIdx.x;

  if (blockIdx.x < Bn) {
    // ---------------- producer: serial scan for row b ----------------
    __builtin_amdgcn_s_setprio(3);
    const int b = blockIdx.x;
    const float4* __restrict__ arow =
        reinterpret_cast<const float4*>(alphas + (size_t)b * Tn);
    constexpr int CV = TCHUNK / 4;   // 10 float4 per chunk

    float integrate = 0.0f;
    int   fc        = 0;

    float4 cur[CV], nxt[CV];
#pragma unroll
    for (int i = 0; i < CV; ++i) cur[i] = arow[i];

    for (int c = 0; c < NTCH; ++c) {
      if (c + 1 < NTCH) {
#pragma unroll
        for (int i = 0; i < CV; ++i) nxt[i] = arow[(c + 1) * CV + i];
      }
      if (lane == 0) {   // publish chunk-c START state (one 8-B relaxed store)
        const uint64_t v = ((uint64_t)__float_as_uint(integrate) << 32) |
                           (uint64_t)(PUBF | (unsigned)fc);
        __hip_atomic_store(&meta[(size_t)b * MSTRIDE + c], v,
                           __ATOMIC_RELAXED, __HIP_MEMORY_SCOPE_AGENT);
      }
#pragma unroll
      for (int i = 0; i < CV; ++i) {
        const float a4[4] = {cur[i].x, cur[i].y, cur[i].z, cur[i].w};
#pragma unroll
        for (int j = 0; j < 4; ++j) {
          const float integ = integrate + a4[j];    // reference op order
          const bool  fire  = integ > kThresh;
          integrate = fire ? (integ - 1.0f) : integ;
          fc += fire ? 1 : 0;
        }
      }
#pragma unroll
      for (int i = 0; i < CV; ++i) cur[i] = nxt[i];
    }
    return;
  }

  // ---------------- consumer: (chunk tc, row b) ----------------
  const int idx = blockIdx.x - Bn;
  const int b   = idx & (Bn - 1);
  const int tc  = idx >> 5;                 // low blockIdx -> low tc
  const int t_start = tc * TCHUNK;
  const int col = lane * 8;                 // 8 floats/thread over H=512

  auto wait_meta = [&](int c) -> uint64_t {
    const uint64_t* p = &meta[(size_t)b * MSTRIDE + c];
    uint64_t v;
    for (;;) {
      v = __hip_atomic_load(p, __ATOMIC_RELAXED, __HIP_MEMORY_SCOPE_AGENT);
      if ((unsigned)v & PUBF) break;
      __builtin_amdgcn_s_sleep(16);
    }
    return v;
  };

  // Chunk-start state (bit-exact from producer).
  float I; int s;
  if (tc == 0) { I = 0.0f; s = 0; }
  else {
    const uint64_t v = wait_meta(tc);
    I = __uint_as_float((unsigned)(v >> 32));
    s = (int)((unsigned)v & 0xFFFFu);
  }

  // Walk back: find t_prev (last fire before t_start) and its remainder.
  int   t_prev   = -1;
  float rem_prev = 0.0f;
  for (int k = 1; tc - k >= 0 && t_prev < 0; ++k) {
    const int ck = tc - k;
    float Ik;
    if (ck == 0) Ik = 0.0f;
    else {
      const uint64_t v = wait_meta(ck);
      Ik = __uint_as_float((unsigned)(v >> 32));
    }
    float q[TCHUNK];
    const float4* a4 = reinterpret_cast<const float4*>(
        alphas + (size_t)b * Tn + ck * TCHUNK);
#pragma unroll
    for (int i = 0; i < TCHUNK / 4; ++i) {
      const float4 v4 = a4[i];
      q[4 * i + 0] = v4.x; q[4 * i + 1] = v4.y;
      q[4 * i + 2] = v4.z; q[4 * i + 3] = v4.w;
    }
    int lt = -1; float lrem = 0.0f;
#pragma unroll
    for (int j = 0; j < TCHUNK; ++j) {
      const float a     = q[j];
      const float integ = Ik + a;            // reference op order
      const bool  fire  = integ > kThresh;
      if (fire) { lt = ck * TCHUNK + j; lrem = a - (1.0f - Ik); }
      Ik = fire ? (integ - 1.0f) : integ;
    }
    if (lt >= 0) { t_prev = lt; rem_prev = lrem; }
  }

  // Stage this chunk's alphas.
  float av[TCHUNK];
  {
    const float4* a4 = reinterpret_cast<const float4*>(
        alphas + (size_t)b * Tn + t_start);
#pragma unroll
    for (int i = 0; i < TCHUNK / 4; ++i) {
      const float4 v4 = a4[i];
      av[4 * i + 0] = v4.x; av[4 * i + 1] = v4.y;
      av[4 * i + 2] = v4.z; av[4 * i + 3] = v4.w;
    }
  }

  const float* __restrict__ hb = hidden + (size_t)b * Tn * Hn + col;
  float4 acc0 = make_float4(0.f, 0.f, 0.f, 0.f);
  float4 acc1 = make_float4(0.f, 0.f, 0.f, 0.f);
  float4 h0, h1;

  auto loadh = [&](int t) {
    h0 = *reinterpret_cast<const float4*>(hb + (size_t)t * Hn);
    h1 = *reinterpret_cast<const float4*>(hb + (size_t)t * Hn + 4);
  };
  auto acc8 = [&](float wt) {
    acc0.x += wt * h0.x; acc0.y += wt * h0.y;
    acc0.z += wt * h0.z; acc0.w += wt * h0.w;
    acc1.x += wt * h1.x; acc1.y += wt * h1.y;
    acc1.z += wt * h1.z; acc1.w += wt * h1.w;
  };
  auto set8 = [&](float wt) {
    acc0.x = wt * h0.x; acc0.y = wt * h0.y;
    acc0.z = wt * h0.z; acc0.w = wt * h0.w;
    acc1.x = wt * h1.x; acc1.y = wt * h1.y;
    acc1.z = wt * h1.z; acc1.w = wt * h1.w;
  };

  if (t_prev >= 0) {            // opening: frame = rem * h[t_prev]
    loadh(t_prev);
    set8(rem_prev);
  }
  for (int t = t_prev + 1; t < t_start; ++t) {   // straddler interior rows
    const float a = alphas[(size_t)b * Tn + t];
    loadh(t);
    acc8(a);
  }

  // Replay chunk tc; close (and exclusively store) each segment that fires.
#pragma unroll
  for (int j = 0; j < TCHUNK; ++j) {
    const int   t     = t_start + j;
    const float a     = av[j];
    const float integ = I + a;               // reference op order
    const bool  fire  = integ > kThresh;     // wave-uniform
    loadh(t);
    if (fire) {
      const float cw = 1.0f - I;             // dist_completion
      acc8(cw);
      if (s < Ln) {
        float* op = out + ((size_t)b * Ln + s) * Hn + col;
        *reinterpret_cast<float4*>(op)     = acc0;
        *reinterpret_cast<float4*>(op + 4) = acc1;
      }
      const float rem = a - cw;              // remainds -> opens next segment
      set8(rem);
      s += 1;
      I  = integ - 1.0f;
    } else {
      acc8(a);
      I = integ;
    }
  }
  // Open tail is owned by consumer (tc+1); nothing more to store...
  if (tc == NTCH - 1) {                      // ...except zero-fill at the end
    const float4 z = make_float4(0.f, 0.f, 0.f, 0.f);
    for (int s2 = s; s2 < Ln; ++s2) {
      float* op = out + ((size_t)b * Ln + s2) * Hn + col;
      *reinterpret_cast<float4*>(op)     = z;
      *reinterpret_cast<float4*>(op + 4) = z;
    }
  }
}

extern "C" void kernel_launch(void* const* d_in, const int* in_sizes, int n_in,
                              void* d_out, int out_size, void* d_ws, size_t ws_size,
                              hipStream_t stream) {
  const float* hidden = (const float*)d_in[0];
  const float* alphas = (const float*)d_in[1];
  float* out = (float*)d_out;

  // ws layout: meta[Bn*MSTRIDE] u64 (16 KB, memset each call -- poison 0xAA
  // would read as published since bit30 of 0xAAAAAAAA is set).
  uint64_t* meta = (uint64_t*)d_ws;
  hipMemsetAsync(meta, 0, (size_t)Bn * MSTRIDE * sizeof(uint64_t), stream);

  const int nblocks = Bn + NTCH * Bn;   // 32 producers + 1600 consumers
  cif_fused_kernel<<<nblocks, 64, 0, stream>>>(hidden, alphas, meta, out);
}

// Round 19
// 69.686 us; speedup vs baseline: 2.6698x; 1.0047x over previous
//
#include <hip/hip_runtime.h>
#include <stdint.h>

static constexpr int   Bn      = 32;
static constexpr int   Tn      = 2000;
static constexpr int   Hn      = 512;
static constexpr int   Ln      = 256;     // max_label_len
static constexpr float kThresh = 0.95f;
static constexpr int   TCHUNK  = 40;
static constexpr int   NTCH    = Tn / TCHUNK;   // 50
static constexpr int   MSTRIDE = 64;            // meta entries per row (padded)
static constexpr unsigned PUBF = 0x40000000u;   // published flag (low word)

// ---------------------------------------------------------------------------
// Fused producer-consumer CIF, exclusive-ownership design. R19 = R18 with
// ONE change: __launch_bounds__(64, 1). Regalloc evidence across the
// session: (64,1) kernels always got honest VGPRs (R10/R13/R14: 132; R16's
// dual-role ran its scan at full speed), while no-bounds/128thr, (256,1),
// and (64,2) all collapsed to 8-28 VGPRs and spilled the producer's
// double-buffer into the serial chain (R9: 12, R12: 8, R15: 28, R18: 20).
//
// Deadlock safety under (64,1): producers are workgroups 0..31 -> dispatched
// and resident first; any resident consumer's meta is eventually published,
// so it completes and retires, freeing slots for later consumers -> forward
// progress without requiring all 1632 blocks co-resident.
//
// Producers (blocks 0..31): register-only serial chain; per 40-step chunk,
// lane 0 publishes ONE relaxed 8-B atomic (integrate_bits | PUB|fc). The
// meta IS the flag -> no release fence, no vmcnt drain in the chain.
// Consumers (one per (chunk tc, row b)): spin on meta[tc], bit-exact replay,
// exclusively own segments that CLOSE in chunk tc (walk-back re-derives the
// straddler's opening), ascending-t accumulation (R8's absmax-0.0 form),
// plain stores; tc=49 zero-fills [fc,256). No atomics, no pre-zero.
// ---------------------------------------------------------------------------
__global__ __launch_bounds__(64, 1) void cif_fused_kernel(
    const float* __restrict__ hidden,
    const float* __restrict__ alphas,
    uint64_t* __restrict__ meta,     // [Bn*MSTRIDE]
    float* __restrict__ out) {
  const int lane = threadIdx.x;

  if (blockIdx.x < Bn) {
    // ---------------- producer: serial scan for row b ----------------
    __builtin_amdgcn_s_setprio(3);
    const int b = blockIdx.x;
    const float4* __restrict__ arow =
        reinterpret_cast<const float4*>(alphas + (size_t)b * Tn);
    constexpr int CV = TCHUNK / 4;   // 10 float4 per chunk

    float integrate = 0.0f;
    int   fc        = 0;

    float4 cur[CV], nxt[CV];
#pragma unroll
    for (int i = 0; i < CV; ++i) cur[i] = arow[i];

    for (int c = 0; c < NTCH; ++c) {
      if (c + 1 < NTCH) {
#pragma unroll
        for (int i = 0; i < CV; ++i) nxt[i] = arow[(c + 1) * CV + i];
      }
      if (lane == 0) {   // publish chunk-c START state (one 8-B relaxed store)
        const uint64_t v = ((uint64_t)__float_as_uint(integrate) << 32) |
                           (uint64_t)(PUBF | (unsigned)fc);
        __hip_atomic_store(&meta[(size_t)b * MSTRIDE + c], v,
                           __ATOMIC_RELAXED, __HIP_MEMORY_SCOPE_AGENT);
      }
#pragma unroll
      for (int i = 0; i < CV; ++i) {
        const float a4[4] = {cur[i].x, cur[i].y, cur[i].z, cur[i].w};
#pragma unroll
        for (int j = 0; j < 4; ++j) {
          const float integ = integrate + a4[j];    // reference op order
          const bool  fire  = integ > kThresh;
          integrate = fire ? (integ - 1.0f) : integ;
          fc += fire ? 1 : 0;
        }
      }
#pragma unroll
      for (int i = 0; i < CV; ++i) cur[i] = nxt[i];
    }
    return;
  }

  // ---------------- consumer: (chunk tc, row b) ----------------
  const int idx = blockIdx.x - Bn;
  const int b   = idx & (Bn - 1);
  const int tc  = idx >> 5;                 // low blockIdx -> low tc
  const int t_start = tc * TCHUNK;
  const int col = lane * 8;                 // 8 floats/thread over H=512

  auto wait_meta = [&](int c) -> uint64_t {
    const uint64_t* p = &meta[(size_t)b * MSTRIDE + c];
    uint64_t v;
    for (;;) {
      v = __hip_atomic_load(p, __ATOMIC_RELAXED, __HIP_MEMORY_SCOPE_AGENT);
      if ((unsigned)v & PUBF) break;
      __builtin_amdgcn_s_sleep(16);
    }
    return v;
  };

  // Chunk-start state (bit-exact from producer).
  float I; int s;
  if (tc == 0) { I = 0.0f; s = 0; }
  else {
    const uint64_t v = wait_meta(tc);
    I = __uint_as_float((unsigned)(v >> 32));
    s = (int)((unsigned)v & 0xFFFFu);
  }

  // Walk back: find t_prev (last fire before t_start) and its remainder.
  int   t_prev   = -1;
  float rem_prev = 0.0f;
  for (int k = 1; tc - k >= 0 && t_prev < 0; ++k) {
    const int ck = tc - k;
    float Ik;
    if (ck == 0) Ik = 0.0f;
    else {
      const uint64_t v = wait_meta(ck);
      Ik = __uint_as_float((unsigned)(v >> 32));
    }
    float q[TCHUNK];
    const float4* a4 = reinterpret_cast<const float4*>(
        alphas + (size_t)b * Tn + ck * TCHUNK);
#pragma unroll
    for (int i = 0; i < TCHUNK / 4; ++i) {
      const float4 v4 = a4[i];
      q[4 * i + 0] = v4.x; q[4 * i + 1] = v4.y;
      q[4 * i + 2] = v4.z; q[4 * i + 3] = v4.w;
    }
    int lt = -1; float lrem = 0.0f;
#pragma unroll
    for (int j = 0; j < TCHUNK; ++j) {
      const float a     = q[j];
      const float integ = Ik + a;            // reference op order
      const bool  fire  = integ > kThresh;
      if (fire) { lt = ck * TCHUNK + j; lrem = a - (1.0f - Ik); }
      Ik = fire ? (integ - 1.0f) : integ;
    }
    if (lt >= 0) { t_prev = lt; rem_prev = lrem; }
  }

  // Stage this chunk's alphas.
  float av[TCHUNK];
  {
    const float4* a4 = reinterpret_cast<const float4*>(
        alphas + (size_t)b * Tn + t_start);
#pragma unroll
    for (int i = 0; i < TCHUNK / 4; ++i) {
      const float4 v4 = a4[i];
      av[4 * i + 0] = v4.x; av[4 * i + 1] = v4.y;
      av[4 * i + 2] = v4.z; av[4 * i + 3] = v4.w;
    }
  }

  const float* __restrict__ hb = hidden + (size_t)b * Tn * Hn + col;
  float4 acc0 = make_float4(0.f, 0.f, 0.f, 0.f);
  float4 acc1 = make_float4(0.f, 0.f, 0.f, 0.f);
  float4 h0, h1;

  auto loadh = [&](int t) {
    h0 = *reinterpret_cast<const float4*>(hb + (size_t)t * Hn);
    h1 = *reinterpret_cast<const float4*>(hb + (size_t)t * Hn + 4);
  };
  auto acc8 = [&](float wt) {
    acc0.x += wt * h0.x; acc0.y += wt * h0.y;
    acc0.z += wt * h0.z; acc0.w += wt * h0.w;
    acc1.x += wt * h1.x; acc1.y += wt * h1.y;
    acc1.z += wt * h1.z; acc1.w += wt * h1.w;
  };
  auto set8 = [&](float wt) {
    acc0.x = wt * h0.x; acc0.y = wt * h0.y;
    acc0.z = wt * h0.z; acc0.w = wt * h0.w;
    acc1.x = wt * h1.x; acc1.y = wt * h1.y;
    acc1.z = wt * h1.z; acc1.w = wt * h1.w;
  };

  if (t_prev >= 0) {            // opening: frame = rem * h[t_prev]
    loadh(t_prev);
    set8(rem_prev);
  }
  for (int t = t_prev + 1; t < t_start; ++t) {   // straddler interior rows
    const float a = alphas[(size_t)b * Tn + t];
    loadh(t);
    acc8(a);
  }

  // Replay chunk tc; close (and exclusively store) each segment that fires.
#pragma unroll
  for (int j = 0; j < TCHUNK; ++j) {
    const int   t     = t_start + j;
    const float a     = av[j];
    const float integ = I + a;               // reference op order
    const bool  fire  = integ > kThresh;     // wave-uniform
    loadh(t);
    if (fire) {
      const float cw = 1.0f - I;             // dist_completion
      acc8(cw);
      if (s < Ln) {
        float* op = out + ((size_t)b * Ln + s) * Hn + col;
        *reinterpret_cast<float4*>(op)     = acc0;
        *reinterpret_cast<float4*>(op + 4) = acc1;
      }
      const float rem = a - cw;              // remainds -> opens next segment
      set8(rem);
      s += 1;
      I  = integ - 1.0f;
    } else {
      acc8(a);
      I = integ;
    }
  }
  // Open tail is owned by consumer (tc+1); nothing more to store...
  if (tc == NTCH - 1) {                      // ...except zero-fill at the end
    const float4 z = make_float4(0.f, 0.f, 0.f, 0.f);
    for (int s2 = s; s2 < Ln; ++s2) {
      float* op = out + ((size_t)b * Ln + s2) * Hn + col;
      *reinterpret_cast<float4*>(op)     = z;
      *reinterpret_cast<float4*>(op + 4) = z;
    }
  }
}

extern "C" void kernel_launch(void* const* d_in, const int* in_sizes, int n_in,
                              void* d_out, int out_size, void* d_ws, size_t ws_size,
                              hipStream_t stream) {
  const float* hidden = (const float*)d_in[0];
  const float* alphas = (const float*)d_in[1];
  float* out = (float*)d_out;

  // ws layout: meta[Bn*MSTRIDE] u64 (16 KB, memset each call -- poison 0xAA
  // would read as published since bit30 of 0xAAAAAAAA is set).
  uint64_t* meta = (uint64_t*)d_ws;
  hipMemsetAsync(meta, 0, (size_t)Bn * MSTRIDE * sizeof(uint64_t), stream);

  const int nblocks = Bn + NTCH * Bn;   // 32 producers + 1600 consumers
  cif_fused_kernel<<<nblocks, 64, 0, stream>>>(hidden, alphas, meta, out);
}

// Round 20
// 63.795 us; speedup vs baseline: 2.9163x; 1.0923x over previous
//
#include <hip/hip_runtime.h>
#include <stdint.h>

static constexpr int   Bn      = 32;
static constexpr int   Tn      = 2000;
static constexpr int   Hn      = 512;
static constexpr int   Ln      = 256;     // max_label_len
static constexpr float kThresh = 0.95f;
static constexpr int   TCHUNK  = 40;      // meta granularity (consumer chunk)
static constexpr int   NTCH    = Tn / TCHUNK;   // 50
static constexpr int   PCH     = 20;      // producer inner chunk (floats)
static constexpr int   NPCH    = Tn / PCH;      // 100
static constexpr int   MSTRIDE = 64;            // meta entries per row (padded)
static constexpr unsigned PUBF = 0x40000000u;   // published flag (low word)

// ---------------------------------------------------------------------------
// Fused producer-consumer CIF, low-register redesign.
// R18/R19 showed the kernel-wide allocator collapses to ~20 VGPRs whenever a
// register-hungry producer shares a kernel with a complex consumer path
// (R9=12, R12=8, R18=20, R19=20; only simple-second-path R16 ran full speed).
// Can't control the allocator -> make BOTH paths fit tiny budgets:
//
// Producer (blocks 0..31): stage the 8 KB alpha row into LDS ONCE (coalesced
// float4, outside the chain), then run the serial chain from LDS in 20-float
// double-buffered chunks (ds_read = lgkm counter, never a vmcnt drain; 20
// steps x ~12 cyc covers the ~120 cyc LDS latency). This also removes the
// per-chunk HBM-miss stall that made R10's scan 46 cyc/step (12-cyc chain +
// ~900-cyc miss / 40 steps) -- predicted producer ~13-17 us. Publishes the
// exact (integrate, fc) state every 40 steps as ONE relaxed 8-B atomic (the
// meta IS the flag; no fence, no vmcnt in chain -- proven R18/R19).
//
// Consumer (one per (chunk tc, row b)): ARRAY-FREE replay -- alphas read as
// scalar uniform loads (L2 broadcast) instead of av[40]/q[40] register
// staging (the other scratch source). Exclusive ownership unchanged from
// R18/R19 (absmax 0.0): owns segments CLOSING in chunk tc, walk-back
// re-derives the straddler opening, ascending-t accumulation, plain stores,
// tc=49 zero-fills [fc,256). No atomics, no pre-zero pass.
// ---------------------------------------------------------------------------
__global__ __launch_bounds__(64, 1) void cif_fused_kernel(
    const float* __restrict__ hidden,
    const float* __restrict__ alphas,
    uint64_t* __restrict__ meta,     // [Bn*MSTRIDE]
    float* __restrict__ out) {
  const int lane = threadIdx.x;
  __shared__ __align__(16) float alds[Tn];   // 8 KB (producer blocks only)

  if (blockIdx.x < Bn) {
    // ---------------- producer: serial scan for row b ----------------
    __builtin_amdgcn_s_setprio(3);
    const int b = blockIdx.x;
    {  // stage row -> LDS, coalesced, one waitcnt (outside the chain)
      const float4* __restrict__ arow =
          reinterpret_cast<const float4*>(alphas + (size_t)b * Tn);
      for (int i = lane; i < Tn / 4; i += 64)
        *reinterpret_cast<float4*>(&alds[4 * i]) = arow[i];
    }
    __syncthreads();

    float I  = 0.0f;
    int   fc = 0;
    float cur[PCH], nxt[PCH];
#pragma unroll
    for (int i = 0; i < PCH / 4; ++i) {
      const float4 v = *reinterpret_cast<const float4*>(&alds[4 * i]);
      cur[4 * i + 0] = v.x; cur[4 * i + 1] = v.y;
      cur[4 * i + 2] = v.z; cur[4 * i + 3] = v.w;
    }
    for (int c = 0; c < NPCH; ++c) {
      if (c + 1 < NPCH) {
#pragma unroll
        for (int i = 0; i < PCH / 4; ++i) {
          const float4 v = *reinterpret_cast<const float4*>(
              &alds[(c + 1) * PCH + 4 * i]);
          nxt[4 * i + 0] = v.x; nxt[4 * i + 1] = v.y;
          nxt[4 * i + 2] = v.z; nxt[4 * i + 3] = v.w;
        }
      }
      if ((c & 1) == 0 && lane == 0) {   // state at t = c*20 = (c/2)*40
        const uint64_t v = ((uint64_t)__float_as_uint(I) << 32) |
                           (uint64_t)(PUBF | (unsigned)fc);
        __hip_atomic_store(&meta[(size_t)b * MSTRIDE + (c >> 1)], v,
                           __ATOMIC_RELAXED, __HIP_MEMORY_SCOPE_AGENT);
      }
#pragma unroll
      for (int j = 0; j < PCH; ++j) {
        const float integ = I + cur[j];         // reference op order
        const bool  fire  = integ > kThresh;
        I  = fire ? (integ - 1.0f) : integ;
        fc += fire ? 1 : 0;
      }
#pragma unroll
      for (int i = 0; i < PCH; ++i) cur[i] = nxt[i];
    }
    return;
  }

  // ---------------- consumer: (chunk tc, row b), array-free ----------------
  const int idx = blockIdx.x - Bn;
  const int b   = idx & (Bn - 1);
  const int tc  = idx >> 5;                 // low blockIdx -> low tc
  const int t_start = tc * TCHUNK;
  const int col = lane * 8;                 // 8 floats/thread over H=512

  auto wait_meta = [&](int c) -> uint64_t {
    const uint64_t* p = &meta[(size_t)b * MSTRIDE + c];
    uint64_t v;
    for (;;) {
      v = __hip_atomic_load(p, __ATOMIC_RELAXED, __HIP_MEMORY_SCOPE_AGENT);
      if ((unsigned)v & PUBF) break;
      __builtin_amdgcn_s_sleep(16);
    }
    return v;
  };

  const float* __restrict__ arow = alphas + (size_t)b * Tn;

  // Chunk-start state (bit-exact from producer).
  float I; int s;
  if (tc == 0) { I = 0.0f; s = 0; }
  else {
    const uint64_t v = wait_meta(tc);
    I = __uint_as_float((unsigned)(v >> 32));
    s = (int)((unsigned)v & 0xFFFFu);
  }

  // Walk back: find t_prev (last fire before t_start) and its remainder.
  int   t_prev   = -1;
  float rem_prev = 0.0f;
  for (int k = 1; tc - k >= 0 && t_prev < 0; ++k) {
    const int ck = tc - k;
    float Ik;
    if (ck == 0) Ik = 0.0f;
    else {
      const uint64_t v = wait_meta(ck);
      Ik = __uint_as_float((unsigned)(v >> 32));
    }
    const float* __restrict__ ap = arow + ck * TCHUNK;
    int lt = -1; float lrem = 0.0f;
#pragma unroll
    for (int j = 0; j < TCHUNK; ++j) {
      const float a     = ap[j];               // uniform scalar load
      const float integ = Ik + a;              // reference op order
      const bool  fire  = integ > kThresh;
      if (fire) { lt = ck * TCHUNK + j; lrem = a - (1.0f - Ik); }
      Ik = fire ? (integ - 1.0f) : integ;
    }
    if (lt >= 0) { t_prev = lt; rem_prev = lrem; }
  }

  const float* __restrict__ hb = hidden + (size_t)b * Tn * Hn + col;
  float4 acc0 = make_float4(0.f, 0.f, 0.f, 0.f);
  float4 acc1 = make_float4(0.f, 0.f, 0.f, 0.f);
  float4 h0, h1;

  auto loadh = [&](int t) {
    h0 = *reinterpret_cast<const float4*>(hb + (size_t)t * Hn);
    h1 = *reinterpret_cast<const float4*>(hb + (size_t)t * Hn + 4);
  };
  auto acc8 = [&](float wt) {
    acc0.x += wt * h0.x; acc0.y += wt * h0.y;
    acc0.z += wt * h0.z; acc0.w += wt * h0.w;
    acc1.x += wt * h1.x; acc1.y += wt * h1.y;
    acc1.z += wt * h1.z; acc1.w += wt * h1.w;
  };
  auto set8 = [&](float wt) {
    acc0.x = wt * h0.x; acc0.y = wt * h0.y;
    acc0.z = wt * h0.z; acc0.w = wt * h0.w;
    acc1.x = wt * h1.x; acc1.y = wt * h1.y;
    acc1.z = wt * h1.z; acc1.w = wt * h1.w;
  };

  if (t_prev >= 0) {            // opening: frame = rem * h[t_prev]
    loadh(t_prev);
    set8(rem_prev);
  }
  for (int t = t_prev + 1; t < t_start; ++t) {   // straddler interior rows
    loadh(t);
    acc8(arow[t]);
  }

  // Replay chunk tc; close (and exclusively store) each segment that fires.
  for (int j = 0; j < TCHUNK; ++j) {
    const int   t     = t_start + j;
    const float a     = arow[t];             // uniform scalar load
    const float integ = I + a;               // reference op order
    const bool  fire  = integ > kThresh;     // wave-uniform
    loadh(t);
    if (fire) {
      const float cw = 1.0f - I;             // dist_completion
      acc8(cw);
      if (s < Ln) {
        float* op = out + ((size_t)b * Ln + s) * Hn + col;
        *reinterpret_cast<float4*>(op)     = acc0;
        *reinterpret_cast<float4*>(op + 4) = acc1;
      }
      const float rem = a - cw;              // remainds -> opens next segment
      set8(rem);
      s += 1;
      I  = integ - 1.0f;
    } else {
      acc8(a);
      I = integ;
    }
  }
  // Open tail is owned by consumer (tc+1); nothing more to store...
  if (tc == NTCH - 1) {                      // ...except zero-fill at the end
    const float4 z = make_float4(0.f, 0.f, 0.f, 0.f);
    for (int s2 = s; s2 < Ln; ++s2) {
      float* op = out + ((size_t)b * Ln + s2) * Hn + col;
      *reinterpret_cast<float4*>(op)     = z;
      *reinterpret_cast<float4*>(op + 4) = z;
    }
  }
}

extern "C" void kernel_launch(void* const* d_in, const int* in_sizes, int n_in,
                              void* d_out, int out_size, void* d_ws, size_t ws_size,
                              hipStream_t stream) {
  const float* hidden = (const float*)d_in[0];
  const float* alphas = (const float*)d_in[1];
  float* out = (float*)d_out;

  // ws layout: meta[Bn*MSTRIDE] u64 (16 KB, memset each call -- poison 0xAA
  // would read as published since bit30 of 0xAAAAAAAA is set).
  uint64_t* meta = (uint64_t*)d_ws;
  hipMemsetAsync(meta, 0, (size_t)Bn * MSTRIDE * sizeof(uint64_t), stream);

  const int nblocks = Bn + NTCH * Bn;   // 32 producers + 1600 consumers
  cif_fused_kernel<<<nblocks, 64, 0, stream>>>(hidden, alphas, meta, out);
}